// Round 6
// baseline (374.390 us; speedup 1.0000x reference)
//
#include <hip/hip_runtime.h>
#include <hip/hip_bf16.h>
#include <stdint.h>

// Problem constants (from reference): B=2048, C=200, F=32, H=256.
// All tensors fp32. M = B*C = 409600 rows of 32 features, contiguous in x.
#define M_ROWS 409600
#define B_CNT  2048
#define C_CNT  200
#define GRID_B 768        // 3 blocks/CU x 256 CUs: guaranteed co-resident
                          // (LDS 39.5KB <= 53.3KB/block, 12 waves/CU, VGPR<=170)

typedef __attribute__((ext_vector_type(8))) short bf16x8;   // 8 bf16 = 4 VGPRs
typedef __attribute__((ext_vector_type(4))) float f32x4;

// round-to-nearest-even f32 -> bf16 bits
__device__ __forceinline__ ushort f2bf(float f) {
    uint32_t u = __float_as_uint(f);
    u += 0x7fffu + ((u >> 16) & 1u);
    return (ushort)(u >> 16);
}

__device__ __forceinline__ f32x4 mfma16(bf16x8 a, bf16x8 b, f32x4 c) {
    return __builtin_amdgcn_mfma_f32_16x16x32_bf16(a, b, c, 0, 0, 0);
}

// ---------------------------------------------------------------------------
// ONE persistent kernel: Phase A (x->bf16 + S/I extract + inflow + W-transpose)
// -> device-scope grid barrier -> Phase B (fused MLP, grid-stride over tiles).
// MFMA 16x16x32 frags: A[m=lane&15][k=q*8+j], B[k=q*8+j][n=lane&15],
// C/D col=lane&15, row=q*4+reg.
// ---------------------------------------------------------------------------
__global__ __launch_bounds__(256, 3) void fused_kernel(
    const float* __restrict__ x,
    const float* __restrict__ T,
    const float* __restrict__ b1,
    const float* __restrict__ b2,
    const float* __restrict__ W1,
    const float* __restrict__ W2,
    const float* __restrict__ W3,
    const float* __restrict__ b3,
    ushort* __restrict__ xb16,
    float* __restrict__ Sc, float* __restrict__ Ic,
    float* __restrict__ sinW, float* __restrict__ iinW,
    ushort* __restrict__ W1t, ushort* __restrict__ W2t,
    unsigned* __restrict__ cnt,
    float* __restrict__ out) {
    constexpr int RS = 264;  // h1 row stride: 256+8, rows 16B-aligned
    __shared__ ushort h1s[64 * RS];          // 33792 B
    __shared__ float b1f[256], b2f[256], w3f[256];
    __shared__ float lamb_part[4][64];
    __shared__ float Sr[C_CNT], Ir[C_CNT];   // +1600 B -> 39488 B total

    const int tid  = threadIdx.x;
    const int blk  = blockIdx.x;
    const int w    = tid >> 6;
    const int lane = tid & 63;
    const int L    = lane & 15;
    const int q    = lane >> 4;

    // ================= Phase A =================
    // (1) weight transposes, spread over first 288 blocks (1 elem/thread)
    {
        int gid = blk * 256 + tid;
        if (gid < 65536) {
            int n = gid >> 8, k = gid & 255;
            W2t[n * 256 + k] = f2bf(W2[k * 256 + n]);   // write coalesced
        } else if (gid < 65536 + 8192) {
            int idx = gid - 65536;
            int n = idx >> 5, k = idx & 31;
            W1t[idx] = f2bf(W1[k * 256 + n]);
        }
    }
    // (2) per batch-row: stream x (convert to bf16), extract exact S/I,
    //     then compute that row's inflow with T coalesced from L2.
    for (int b = blk; b < B_CNT; b += GRID_B) {
        const float4* xr = (const float4*)(x + (size_t)b * 6400);  // 1600 f4
        ushort4* xw = (ushort4*)(xb16 + (size_t)b * 6400);
        for (int i4 = tid; i4 < 1600; i4 += 256) {
            float4 v = xr[i4];
            ushort4 u;
            u.x = f2bf(v.x); u.y = f2bf(v.y); u.z = f2bf(v.z); u.w = f2bf(v.w);
            xw[i4] = u;
            if ((i4 & 7) == 0) {            // element i4*4 is feature 0 of c
                int c = i4 >> 3;
                Sr[c] = v.x; Ir[c] = v.y;
                Sc[b * C_CNT + c] = v.x;
                Ic[b * C_CNT + c] = v.y;
            }
        }
        __syncthreads();
        if (tid < C_CNT) {
            float as = 0.f, ai = 0.f;
#pragma unroll 4
            for (int cp = 0; cp < C_CNT; ++cp) {
                float tv = T[cp * C_CNT + tid];   // coalesced over tid, L2-hot
                as = fmaf(Sr[cp], tv, as);
                ai = fmaf(Ir[cp], tv, ai);
            }
            sinW[b * C_CNT + tid] = as;
            iinW[b * C_CNT + tid] = ai;
        }
        __syncthreads();   // Sr/Ir reused next row
    }
    // stage biases for phase B (visible after barrier's __syncthreads)
    b1f[tid] = b1[tid];
    b2f[tid] = b2[tid];
    w3f[tid] = W3[tid];

    // ================= grid barrier (device scope) =================
    __syncthreads();
    if (tid == 0) {
        __threadfence();                      // publish this block's writes
        atomicAdd(cnt, 1u);
        int spin = 0;
        while (atomicAdd(cnt, 0u) < (unsigned)GRID_B) {
            __builtin_amdgcn_s_sleep(8);
            if (++spin > (1 << 20)) break;    // hang-valve (>0.2s, never legit)
        }
    }
    __syncthreads();
    __threadfence();                          // acquire: see other blocks' data

    // ================= Phase B: MLP tiles (R3 body) =================
    // W1t A-frags are tile-invariant: hoist out of the tile loop.
    bf16x8 aw[4];
#pragma unroll
    for (int i = 0; i < 4; ++i)
        aw[i] = *(const bf16x8*)(W1t + (64 * w + i * 16 + L) * 32 + q * 8);

    for (int tile = blk; tile < M_ROWS / 64; tile += GRID_B) {
        const int m0 = tile * 64;

        // ---- GEMM1 (K=32): B-frags from bf16 xb16 ----
        bf16x8 bx[4];
#pragma unroll
        for (int i = 0; i < 4; ++i)
            bx[i] = *(const bf16x8*)(xb16 + (size_t)(m0 + i * 16 + L) * 32 + q * 8);
        f32x4 acc1[4][4];
#pragma unroll
        for (int i1 = 0; i1 < 4; ++i1)
#pragma unroll
            for (int im = 0; im < 4; ++im)
                acc1[i1][im] = mfma16(aw[i1], bx[im], (f32x4){0.f, 0.f, 0.f, 0.f});

        __syncthreads();  // prev tile's lamb_part/h1s reads done before rewrite

        // fp32 bias + relu, one bf16 rounding; 4 consecutive n1 -> ds_write_b64
#pragma unroll
        for (int i1 = 0; i1 < 4; ++i1) {
            int n1b = 64 * w + i1 * 16 + q * 4;
#pragma unroll
            for (int im = 0; im < 4; ++im) {
                int m = im * 16 + L;
                float v0 = fmaxf(acc1[i1][im][0] + b1f[n1b + 0], 0.f);
                float v1 = fmaxf(acc1[i1][im][1] + b1f[n1b + 1], 0.f);
                float v2 = fmaxf(acc1[i1][im][2] + b1f[n1b + 2], 0.f);
                float v3 = fmaxf(acc1[i1][im][3] + b1f[n1b + 3], 0.f);
                uint2 pk;
                pk.x = (uint32_t)f2bf(v0) | ((uint32_t)f2bf(v1) << 16);
                pk.y = (uint32_t)f2bf(v2) | ((uint32_t)f2bf(v3) << 16);
                *reinterpret_cast<uint2*>(&h1s[m * RS + n1b]) = pk;
            }
        }
        __syncthreads();

        // ---- GEMM2 (K=256, 8 k-chunks): A from W2t (L2-hot), B from LDS ----
        f32x4 acc2[4][4];
#pragma unroll
        for (int i2 = 0; i2 < 4; ++i2)
#pragma unroll
            for (int im = 0; im < 4; ++im) acc2[i2][im] = (f32x4){0.f, 0.f, 0.f, 0.f};

#pragma unroll
        for (int kc = 0; kc < 8; ++kc) {
            bf16x8 a2[4], bh[4];
#pragma unroll
            for (int i2 = 0; i2 < 4; ++i2) {
                int n2 = 64 * w + i2 * 16 + L;
                a2[i2] = *(const bf16x8*)(W2t + n2 * 256 + kc * 32 + q * 8);
            }
#pragma unroll
            for (int im = 0; im < 4; ++im) {
                int m = im * 16 + L;
                bh[im] = *(const bf16x8*)(&h1s[m * RS + kc * 32 + q * 8]);
            }
#pragma unroll
            for (int i2 = 0; i2 < 4; ++i2)
#pragma unroll
                for (int im = 0; im < 4; ++im)
                    acc2[i2][im] = mfma16(a2[i2], bh[im], acc2[i2][im]);
        }

        // ---- GEMM3: lamb[m] = sum_n2 relu(h2 + b2) * W3 (fp32, exact) ----
        float part[4] = {0.f, 0.f, 0.f, 0.f};
#pragma unroll
        for (int i2 = 0; i2 < 4; ++i2) {
            int n2b = 64 * w + i2 * 16 + q * 4;
#pragma unroll
            for (int im = 0; im < 4; ++im)
#pragma unroll
                for (int r = 0; r < 4; ++r) {
                    float h2 = fmaxf(acc2[i2][im][r] + b2f[n2b + r], 0.f);
                    part[im] = fmaf(h2, w3f[n2b + r], part[im]);
                }
        }
#pragma unroll
        for (int im = 0; im < 4; ++im) {
            float p = part[im];
            p += __shfl_xor(p, 16);
            p += __shfl_xor(p, 32);
            if (q == 0) lamb_part[w][im * 16 + L] = p;
        }
        __syncthreads();

        // ---- epilogue: one thread per row, compact coalesced reads ----
        if (tid < 64) {
            int gm = m0 + tid;
            float lam = lamb_part[0][tid] + lamb_part[1][tid] +
                        lamb_part[2][tid] + lamb_part[3][tid] + b3[0];
            float S = Sc[gm], I = Ic[gm];
            int c = gm % C_CNT;
            float of = 1.0f - T[c * C_CNT + c];
            float sv = sinW[gm], iv = iinW[gm];
            float dS = -lam * S + sv - of * S;
            float dI =  lam * S + iv - of * I;
            float2 o; o.x = S + dS; o.y = I + dI;
            ((float2*)out)[gm] = o;   // 8B store -> out[2gm], out[2gm+1]
        }
    }
}

// ---------------------------------------------------------------------------
extern "C" void kernel_launch(void* const* d_in, const int* in_sizes, int n_in,
                              void* d_out, int out_size, void* d_ws, size_t ws_size,
                              hipStream_t stream) {
    const float* x  = (const float*)d_in[0];
    const float* T  = (const float*)d_in[1];
    const float* W1 = (const float*)d_in[2];
    const float* b1 = (const float*)d_in[3];
    const float* W2 = (const float*)d_in[4];
    const float* b2 = (const float*)d_in[5];
    const float* W3 = (const float*)d_in[6];
    const float* b3 = (const float*)d_in[7];

    // ws layout (32.92 MB total): cnt(256B) | xb16 | Sc Ic sinW iinW | W1t W2t
    char* ws = (char*)d_ws;
    unsigned* cnt = (unsigned*)ws;
    const size_t xb_off  = 256;
    const size_t xb_sz   = (size_t)M_ROWS * 32 * 2;      // 26,214,400
    const size_t f32_arr = (size_t)M_ROWS * 4;           //  1,638,400
    ushort* xb16 = (ushort*)(ws + xb_off);
    float*  Sc   = (float*)(ws + xb_off + xb_sz);
    float*  Ic   = (float*)(ws + xb_off + xb_sz + f32_arr);
    float*  sinW = (float*)(ws + xb_off + xb_sz + 2 * f32_arr);
    float*  iinW = (float*)(ws + xb_off + xb_sz + 3 * f32_arr);
    ushort* W1t  = (ushort*)(ws + xb_off + xb_sz + 4 * f32_arr);
    ushort* W2t  = (ushort*)(ws + xb_off + xb_sz + 4 * f32_arr + 8192 * 2);

    hipMemsetAsync(cnt, 0, 4, stream);   // barrier counter (ws is poisoned 0xAA)
    hipLaunchKernelGGL(fused_kernel, dim3(GRID_B), dim3(256), 0, stream,
                       x, T, b1, b2, W1, W2, W3, b3,
                       xb16, Sc, Ic, sinW, iinW, W1t, W2t, cnt, (float*)d_out);
}

// Round 7
// 332.317 us; speedup vs baseline: 1.1266x; 1.1266x over previous
//
#include <hip/hip_runtime.h>
#include <hip/hip_bf16.h>
#include <stdint.h>

// Problem constants (from reference): B=2048, C=200, F=32, H=256.
// All tensors fp32. M = B*C = 409600 rows of 32 features, contiguous in x.
#define M_ROWS 409600
#define B_CNT  2048
#define C_CNT  200
#define GRID_B 512        // EXACTLY 2 blocks/CU x 256 CUs; co-residency required
                          // by the grid barrier: LDS 71.2KB*2<=160KB, VGPR<=256 (lb 256,2)
#define N_TILE (M_ROWS / 128)   // 3200 tiles of 128 rows

typedef __attribute__((ext_vector_type(8))) short bf16x8;   // 8 bf16 = 4 VGPRs
typedef __attribute__((ext_vector_type(4))) float f32x4;

// round-to-nearest-even f32 -> bf16 bits
__device__ __forceinline__ ushort f2bf(float f) {
    uint32_t u = __float_as_uint(f);
    u += 0x7fffu + ((u >> 16) & 1u);
    return (ushort)(u >> 16);
}

__device__ __forceinline__ f32x4 mfma16(bf16x8 a, bf16x8 b, f32x4 c) {
    return __builtin_amdgcn_mfma_f32_16x16x32_bf16(a, b, c, 0, 0, 0);
}

__device__ __forceinline__ bf16x8 pack8(float4 a, float4 b) {
    bf16x8 r;
    r[0] = (short)f2bf(a.x); r[1] = (short)f2bf(a.y);
    r[2] = (short)f2bf(a.z); r[3] = (short)f2bf(a.w);
    r[4] = (short)f2bf(b.x); r[5] = (short)f2bf(b.y);
    r[6] = (short)f2bf(b.z); r[7] = (short)f2bf(b.w);
    return r;
}

// ---------------------------------------------------------------------------
// ONE persistent kernel.
// Phase A: W1/W2 transpose->bf16; S/I extract (exact fp32) + inflow GEMV.
// Grid barrier: load-only polling (NO RMW storm), release/acquire semantics.
// Phase B: fused MLP, 128-row tiles, 4 waves (wave w owns n in [64w,64w+64)).
// MFMA 16x16x32 frags: A[m=lane&15][k=q*8+j], B[k=q*8+j][n=lane&15],
// C/D col=lane&15, row=q*4+reg.
// ---------------------------------------------------------------------------
__global__ __launch_bounds__(256, 2) void fused_kernel(
    const float* __restrict__ x,
    const float* __restrict__ T,
    const float* __restrict__ b1,
    const float* __restrict__ b2,
    const float* __restrict__ W1,
    const float* __restrict__ W2,
    const float* __restrict__ W3,
    const float* __restrict__ b3,
    float* __restrict__ Sc, float* __restrict__ Ic,
    float* __restrict__ sinW, float* __restrict__ iinW,
    ushort* __restrict__ W1t, ushort* __restrict__ W2t,
    unsigned* __restrict__ cnt,
    float* __restrict__ out) {
    constexpr int RS = 264;  // h1 row stride: 256+8, rows 16B-aligned, 2-way-max banks
    __shared__ ushort h1s[128 * RS];         // 67584 B
    __shared__ float lamb_part[4][128];      //  2048 B
    __shared__ float Sr[C_CNT], Ir[C_CNT];   //  1600 B  -> 71232 B total

    const int tid  = threadIdx.x;
    const int blk  = blockIdx.x;
    const int w    = tid >> 6;
    const int lane = tid & 63;
    const int L    = lane & 15;
    const int q    = lane >> 4;

    // ================= Phase A =================
    // (1) weight transposes on first 288 blocks (1 elem/thread)
    {
        int gid = blk * 256 + tid;
        if (gid < 65536) {
            int n = gid >> 8, k = gid & 255;
            W2t[n * 256 + k] = f2bf(W2[k * 256 + n]);   // write coalesced
        } else if (gid < 65536 + 8192) {
            int idx = gid - 65536;
            int n = idx >> 5, k = idx & 31;
            W1t[idx] = f2bf(W1[k * 256 + n]);
        }
    }
    // (2) 4 batch rows per block: S/I extract + inflow (T coalesced, L2-hot)
    for (int b = blk; b < B_CNT; b += GRID_B) {
        if (tid < C_CNT) {
            float2 si = *(const float2*)(x + (size_t)b * 6400 + tid * 32);
            Sr[tid] = si.x; Ir[tid] = si.y;
            Sc[b * C_CNT + tid] = si.x;
            Ic[b * C_CNT + tid] = si.y;
        }
        __syncthreads();
        if (tid < C_CNT) {
            float as = 0.f, ai = 0.f;
#pragma unroll 8
            for (int cp = 0; cp < C_CNT; ++cp) {
                float tv = T[cp * C_CNT + tid];
                as = fmaf(Sr[cp], tv, as);
                ai = fmaf(Ir[cp], tv, ai);
            }
            sinW[b * C_CNT + tid] = as;
            iinW[b * C_CNT + tid] = ai;
        }
        __syncthreads();
    }

    // ================= grid barrier (load-only poll) =================
    __syncthreads();
    if (tid == 0) {
        __threadfence();   // belt & braces; fetch_add below is ACQ_REL anyway
        __hip_atomic_fetch_add(cnt, 1u, __ATOMIC_ACQ_REL, __HIP_MEMORY_SCOPE_AGENT);
        int spin = 0;
        while (__hip_atomic_load(cnt, __ATOMIC_ACQUIRE, __HIP_MEMORY_SCOPE_AGENT)
               < (unsigned)GRID_B) {
            __builtin_amdgcn_s_sleep(32);               // ~2k cyc between polls
            if (++spin > (1 << 20)) break;              // hang-valve
        }
    }
    __syncthreads();

    // ================= Phase B: MLP, 128-row tiles =================
    // tile-invariant W1t A-frags (written by other blocks -> after barrier)
    bf16x8 aw[4];
#pragma unroll
    for (int i = 0; i < 4; ++i)
        aw[i] = *(const bf16x8*)(W1t + (64 * w + i * 16 + L) * 32 + q * 8);

    for (int tile = blk; tile < N_TILE; tile += GRID_B) {
        const int m0 = tile * 128;

        // ---- GEMM1 (K=32): B-frags packed in-register from fp32 x (L3-hot)
        bf16x8 bx[8];
#pragma unroll
        for (int im = 0; im < 8; ++im) {
            const float4* xr =
                (const float4*)(x + (size_t)(m0 + im * 16 + L) * 32 + q * 8);
            bx[im] = pack8(xr[0], xr[1]);
        }
        f32x4 acc1[4][8];
#pragma unroll
        for (int i1 = 0; i1 < 4; ++i1)
#pragma unroll
            for (int im = 0; im < 8; ++im)
                acc1[i1][im] = mfma16(aw[i1], bx[im], (f32x4){0.f, 0.f, 0.f, 0.f});

        // bias vector for this wave's n-slice (global, L2-broadcast)
        float4 b1v[4];
#pragma unroll
        for (int i1 = 0; i1 < 4; ++i1)
            b1v[i1] = *(const float4*)(b1 + 64 * w + i1 * 16 + q * 4);

        __syncthreads();  // prev tile: h1s reads & lamb_part reads complete

        // fp32 bias + relu, one bf16 rounding; 4 consecutive n1 -> ds_write_b64
#pragma unroll
        for (int i1 = 0; i1 < 4; ++i1) {
            int n1b = 64 * w + i1 * 16 + q * 4;
#pragma unroll
            for (int im = 0; im < 8; ++im) {
                int m = im * 16 + L;
                float v0 = fmaxf(acc1[i1][im][0] + b1v[i1].x, 0.f);
                float v1 = fmaxf(acc1[i1][im][1] + b1v[i1].y, 0.f);
                float v2 = fmaxf(acc1[i1][im][2] + b1v[i1].z, 0.f);
                float v3 = fmaxf(acc1[i1][im][3] + b1v[i1].w, 0.f);
                uint2 pk;
                pk.x = (uint32_t)f2bf(v0) | ((uint32_t)f2bf(v1) << 16);
                pk.y = (uint32_t)f2bf(v2) | ((uint32_t)f2bf(v3) << 16);
                *reinterpret_cast<uint2*>(&h1s[m * RS + n1b]) = pk;
            }
        }
        __syncthreads();

        // ---- GEMM2 (K=256, 8 k-chunks): A from W2t (L2-hot), B from LDS ----
        f32x4 acc2[4][8];
#pragma unroll
        for (int i2 = 0; i2 < 4; ++i2)
#pragma unroll
            for (int im = 0; im < 8; ++im)
                acc2[i2][im] = (f32x4){0.f, 0.f, 0.f, 0.f};

#pragma unroll
        for (int kc = 0; kc < 8; ++kc) {
            bf16x8 a2[4], bh[8];
#pragma unroll
            for (int i2 = 0; i2 < 4; ++i2) {
                int n2 = 64 * w + i2 * 16 + L;
                a2[i2] = *(const bf16x8*)(W2t + n2 * 256 + kc * 32 + q * 8);
            }
#pragma unroll
            for (int im = 0; im < 8; ++im) {
                int m = im * 16 + L;
                bh[im] = *(const bf16x8*)(&h1s[m * RS + kc * 32 + q * 8]);
            }
#pragma unroll
            for (int i2 = 0; i2 < 4; ++i2)
#pragma unroll
                for (int im = 0; im < 8; ++im)
                    acc2[i2][im] = mfma16(a2[i2], bh[im], acc2[i2][im]);
        }

        // ---- GEMM3: lamb[m] = sum_n2 relu(h2 + b2) * W3 (fp32, exact) ----
        float part[8] = {0.f, 0.f, 0.f, 0.f, 0.f, 0.f, 0.f, 0.f};
#pragma unroll
        for (int i2 = 0; i2 < 4; ++i2) {
            float4 b2v = *(const float4*)(b2 + 64 * w + i2 * 16 + q * 4);
            float4 w3v = *(const float4*)(W3 + 64 * w + i2 * 16 + q * 4);
#pragma unroll
            for (int im = 0; im < 8; ++im) {
                part[im] = fmaf(fmaxf(acc2[i2][im][0] + b2v.x, 0.f), w3v.x, part[im]);
                part[im] = fmaf(fmaxf(acc2[i2][im][1] + b2v.y, 0.f), w3v.y, part[im]);
                part[im] = fmaf(fmaxf(acc2[i2][im][2] + b2v.z, 0.f), w3v.z, part[im]);
                part[im] = fmaf(fmaxf(acc2[i2][im][3] + b2v.w, 0.f), w3v.w, part[im]);
            }
        }
#pragma unroll
        for (int im = 0; im < 8; ++im) {
            float p = part[im];
            p += __shfl_xor(p, 16);
            p += __shfl_xor(p, 32);
            if (q == 0) lamb_part[w][im * 16 + L] = p;
        }
        __syncthreads();

        // ---- epilogue: one thread per row, compact coalesced reads ----
        if (tid < 128) {
            int gm = m0 + tid;
            float lam = lamb_part[0][tid] + lamb_part[1][tid] +
                        lamb_part[2][tid] + lamb_part[3][tid] + b3[0];
            float S = Sc[gm], I = Ic[gm];
            int c = gm % C_CNT;
            float of = 1.0f - T[c * C_CNT + c];
            float sv = sinW[gm], iv = iinW[gm];
            float dS = -lam * S + sv - of * S;
            float dI =  lam * S + iv - of * I;
            float2 o; o.x = S + dS; o.y = I + dI;
            ((float2*)out)[gm] = o;   // 8B store -> out[2gm], out[2gm+1]
        }
    }
}

// ---------------------------------------------------------------------------
extern "C" void kernel_launch(void* const* d_in, const int* in_sizes, int n_in,
                              void* d_out, int out_size, void* d_ws, size_t ws_size,
                              hipStream_t stream) {
    const float* x  = (const float*)d_in[0];
    const float* T  = (const float*)d_in[1];
    const float* W1 = (const float*)d_in[2];
    const float* b1 = (const float*)d_in[3];
    const float* W2 = (const float*)d_in[4];
    const float* b2 = (const float*)d_in[5];
    const float* W3 = (const float*)d_in[6];
    const float* b3 = (const float*)d_in[7];

    // ws layout (6.84 MB): cnt(256B) | Sc Ic sinW iinW (4 x 1.6MB) | W1t W2t
    char* ws = (char*)d_ws;
    unsigned* cnt = (unsigned*)ws;
    const size_t f32_arr = (size_t)M_ROWS * 4;
    float*  Sc   = (float*)(ws + 256);
    float*  Ic   = (float*)(ws + 256 + f32_arr);
    float*  sinW = (float*)(ws + 256 + 2 * f32_arr);
    float*  iinW = (float*)(ws + 256 + 3 * f32_arr);
    ushort* W1t  = (ushort*)(ws + 256 + 4 * f32_arr);
    ushort* W2t  = (ushort*)(ws + 256 + 4 * f32_arr + 8192 * 2);

    hipMemsetAsync(cnt, 0, 4, stream);   // barrier counter (ws poisoned 0xAA)
    hipLaunchKernelGGL(fused_kernel, dim3(GRID_B), dim3(256), 0, stream,
                       x, T, b1, b2, W1, W2, W3, b3,
                       Sc, Ic, sinW, iinW, W1t, W2t, cnt, (float*)d_out);
}